// Round 3
// baseline (1074.034 us; speedup 1.0000x reference)
//
#include <hip/hip_runtime.h>
#include <hip/hip_bf16.h>

#define Tn 8192
#define Dn 1024
#define Fn 4096
#define SHn 2048
#define En 16
#define CAPn 1024

typedef __bf16 bf16_t;
typedef bf16_t bf16x8 __attribute__((ext_vector_type(8)));
typedef float f32x4 __attribute__((ext_vector_type(4)));

__device__ __forceinline__ unsigned short f2bf(float f) {
  unsigned int u = __builtin_bit_cast(unsigned int, f);
  u += 0x7FFFu + ((u >> 16) & 1u);
  return (unsigned short)(u >> 16);
}
__device__ __forceinline__ unsigned int pack2(float a, float b) {
  return (unsigned int)f2bf(a) | ((unsigned int)f2bf(b) << 16);
}

__device__ __forceinline__ void gload16(const void* g, void* l) {
  __builtin_amdgcn_global_load_lds(
      (const __attribute__((address_space(1))) unsigned int*)g,
      (__attribute__((address_space(3))) unsigned int*)l, 16, 0, 0);
}

// ---------------- fp32 -> bf16 convert ----------------
__global__ __launch_bounds__(256) void kcvt(const float* __restrict__ s,
                                            unsigned short* __restrict__ d, int n8) {
  int i = blockIdx.x * 256 + threadIdx.x;
  int stride = gridDim.x * 256;
  const float4* sv = (const float4*)s;
  for (; i < n8; i += stride) {
    float4 a = sv[2 * i], b = sv[2 * i + 1];
    uint4 u = { pack2(a.x, a.y), pack2(a.z, a.w), pack2(b.x, b.y), pack2(b.z, b.w) };
    ((uint4*)d)[i] = u;
  }
}

// ---------------- gate scores: sigmoid(x @ gate_w^T), stored [E][T] ----------------
__global__ __launch_bounds__(256) void kscores(const float* __restrict__ x,
                                               const float* __restrict__ gw,
                                               float* __restrict__ sc) {
  __shared__ float sx[Dn];
  int tid = threadIdx.x, tok = blockIdx.x;
  ((float4*)sx)[tid] = ((const float4*)(x + (size_t)tok * Dn))[tid];
  __syncthreads();
  int e = tid >> 4, kl = tid & 15;
  const float4* w = (const float4*)(gw + e * Dn);
  const float4* xv = (const float4*)sx;
  float acc = 0.f;
#pragma unroll
  for (int j = 0; j < 16; ++j) {
    float4 a = w[kl + 16 * j], b = xv[kl + 16 * j];
    acc += a.x * b.x + a.y * b.y + a.z * b.z + a.w * b.w;
  }
#pragma unroll
  for (int off = 8; off; off >>= 1) acc += __shfl_xor(acc, off, 64);
  if (kl == 0) sc[(size_t)e * Tn + tok] = 1.f / (1.f + expf(-acc));
}

// ---------------- per-expert top-CAP radix select (ties: lowest index) ----------------
__global__ __launch_bounds__(256) void kselect(const float* __restrict__ scores,
                                               int* __restrict__ ids,
                                               float* __restrict__ oscore) {
  __shared__ unsigned int keys[Tn];
  __shared__ unsigned int hist[256];
  __shared__ unsigned int sh_prefix, sh_k, sh_cnt, sh_eq;
  __shared__ int eqlist[1024];
  const int tid = threadIdx.x, e = blockIdx.x;
  const float* row = scores + (size_t)e * Tn;
  for (int i = 0; i < Tn / 256; ++i)
    keys[tid + i * 256] = __float_as_uint(row[tid + i * 256]);
  if (tid == 0) { sh_prefix = 0u; sh_k = CAPn; }
  __syncthreads();
  for (int shift = 24; shift >= 0; shift -= 8) {
    hist[tid] = 0u;
    __syncthreads();
    unsigned int prefix = sh_prefix;
    unsigned int mask = (shift == 24) ? 0u : (0xFFFFFFFFu << (shift + 8));
    for (int i = 0; i < Tn / 256; ++i) {
      unsigned int kk = keys[tid + i * 256];
      if ((kk & mask) == prefix) atomicAdd(&hist[(kk >> shift) & 255], 1u);
    }
    __syncthreads();
    if (tid == 0) {
      unsigned int k = sh_k, c = 0; int b;
      for (b = 255; b >= 0; --b) { c += hist[b]; if (c >= k) break; }
      sh_k = k - (c - hist[b]);
      sh_prefix = prefix | ((unsigned int)b << shift);
    }
    __syncthreads();
  }
  const unsigned int thr = sh_prefix;
  if (tid == 0) { sh_cnt = 0u; sh_eq = 0u; }
  __syncthreads();
  const int base = e * CAPn;
  for (int i = 0; i < Tn / 256; ++i) {
    int t = tid + i * 256;
    unsigned int kk = keys[t];
    if (kk > thr) {
      unsigned int p = atomicAdd(&sh_cnt, 1u);
      ids[base + p] = t;
      oscore[base + p] = __uint_as_float(kk);
    } else if (kk == thr) {
      unsigned int p = atomicAdd(&sh_eq, 1u);
      if (p < 1024u) eqlist[p] = t;
    }
  }
  __syncthreads();
  if (tid == 0) {
    int need = CAPn - (int)sh_cnt;
    int m = (int)sh_eq; if (m > 1024) m = 1024;
    for (int j = 0; j < need; ++j) {
      int best = 1 << 30, bi = 0;
      for (int i2 = 0; i2 < m; ++i2)
        if (eqlist[i2] < best) { best = eqlist[i2]; bi = i2; }
      eqlist[bi] = 1 << 30;
      ids[base + (int)sh_cnt + j] = best;
      oscore[base + (int)sh_cnt + j] = __uint_as_float(thr);
    }
  }
}

// =====================================================================
// 8-phase counted-vmcnt GEMM (T1+T2+T3+T4+T5), 512 threads, 8 waves.
// BM=256, BK=64. GLU: BN=128 + two B operands. Down: BN=256, one B.
// EPI: 0 = GLU -> H bf16; 1 = dense fp32 store; 2 = scatter atomicAdd*score
// =====================================================================
template <int BN, int NOPS, bool GATHER, int EPI>
__global__ __launch_bounds__(512, 2) void kgemm8(
    const unsigned short* __restrict__ Ab, const int* __restrict__ idsg,
    const unsigned short* __restrict__ B1b, const unsigned short* __restrict__ B2b,
    const float* __restrict__ bias1, const float* __restrict__ bias2,
    const float* __restrict__ scg, void* __restrict__ OutV,
    int N, int Mz, int K, int MBc, int NBc) {
  constexpr int BM = 256;
  constexpr int NF = (BN / 4) / 16;          // per-wave n fragments
  constexpr int BRPW = BN / 8;               // B rows staged per wave
  constexpr int BISS = BRPW / 8;             // B stage issues per wave (2 or 4)
  constexpr unsigned A_OFF = 0;
  constexpr unsigned B1_OFF = 32768;
  constexpr unsigned B2_OFF = 32768u + (unsigned)BN * 128u;

  __shared__ alignas(16) unsigned char lds[2][65536];
  __shared__ int sIds[BM];
  __shared__ float sSc[BM];

  const int tid = threadIdx.x;
  const int lane = tid & 63, w = tid >> 6;
  const int wm = w >> 2, wn = w & 3;
  const int lrow = lane & 15, lk = lane >> 4;
  const int lr = lane >> 3, lc = lane & 7;
  const int srcb = ((lc ^ lr) << 4);

  const int nwg = gridDim.x;
  const int cpx = nwg >> 3;
  const int bid = blockIdx.x;
  const int swz = (bid & 7) * cpx + (bid >> 3);
  const int bn = swz % NBc;
  const int bm = (swz / NBc) % MBc;
  const int z  = swz / (NBc * MBc);
  const int row0 = bm * BM;

  if (tid < BM) {
    if (GATHER || EPI == 2) {
      sIds[tid] = idsg[z * CAPn + row0 + tid];
      if (EPI == 2) sSc[tid] = scg[z * CAPn + row0 + tid];
    }
  }
  __syncthreads();

  const size_t ks = (size_t)K * 2;  // row stride in bytes
  const unsigned char* Az = (const unsigned char*)Ab + (EPI == 2 ? (size_t)z * Mz * ks : 0);
  const unsigned char* B1z = (const unsigned char*)B1b + (size_t)z * N * ks;
  const unsigned char* B2z = (NOPS == 2) ? (const unsigned char*)B2b + (size_t)z * N * ks : nullptr;

  const unsigned char* aS[4];
#pragma unroll
  for (int i = 0; i < 4; ++i) {
    int rr = w * 32 + 8 * i + lr;
    size_t arow = GATHER ? (size_t)sIds[rr] : (size_t)(row0 + rr);
    aS[i] = Az + arow * ks + srcb;
  }
  const unsigned char* b1S[BISS];
  const unsigned char* b2S[BISS];
#pragma unroll
  for (int i = 0; i < BISS; ++i) {
    int rr = bn * BN + w * BRPW + 8 * i + lr;
    b1S[i] = B1z + (size_t)rr * ks + srcb;
    if (NOPS == 2) b2S[i] = B2z + (size_t)rr * ks + srcb;
  }

  auto STG = [&](int idx, unsigned char* buf, int kb) {
    if (idx < 4) {
      gload16(aS[idx] + kb, buf + A_OFF + (unsigned)(w * 32 + 8 * idx) * 128u);
    } else if (NOPS == 2) {
      if (idx < 6)
        gload16(b1S[idx - 4] + kb, buf + B1_OFF + (unsigned)(w * BRPW + 8 * (idx - 4)) * 128u);
      else
        gload16(b2S[idx - 6] + kb, buf + B2_OFF + (unsigned)(w * BRPW + 8 * (idx - 6)) * 128u);
    } else {
      gload16(b1S[idx - 4] + kb, buf + B1_OFF + (unsigned)(w * BRPW + 8 * (idx - 4)) * 128u);
    }
  };

  f32x4 acc[NOPS][8][NF];
#pragma unroll
  for (int o = 0; o < NOPS; ++o)
#pragma unroll
    for (int m = 0; m < 8; ++m)
#pragma unroll
      for (int n = 0; n < NF; ++n) acc[o][m][n] = {0.f, 0.f, 0.f, 0.f};

  // prologue: stage tile 0 into lds[0]
#pragma unroll
  for (int i = 0; i < 8; ++i) STG(i, lds[0], 0);

  const int NT = K >> 6;
  int c = 0;
  for (int t = 0; t < NT; ++t) {
    unsigned char* bufc = lds[c];
    unsigned char* bufn = lds[c ^ 1];
    const int kb = (t + 1 < NT ? t + 1 : t) * 128;  // dummy re-stage on last iter
    bf16x8 bv[NOPS][NF][2];
#pragma unroll
    for (int p = 0; p < 4; ++p) {
      STG(2 * p, bufn, kb);
      STG(2 * p + 1, bufn, kb);
      if (p == 0) {
        asm volatile("s_waitcnt vmcnt(2)" ::: "memory");
        __builtin_amdgcn_s_barrier();
        __builtin_amdgcn_sched_barrier(0);
#pragma unroll
        for (int n = 0; n < NF; ++n)
#pragma unroll
          for (int kk = 0; kk < 2; ++kk) {
            unsigned off = (unsigned)(wn * (BN / 4) + n * 16 + lrow) * 128u +
                           ((unsigned)((kk * 4 + lk) ^ (lrow & 7)) << 4);
            bv[0][n][kk] = *(const bf16x8*)(bufc + B1_OFF + off);
            if (NOPS == 2) bv[1][n][kk] = *(const bf16x8*)(bufc + B2_OFF + off);
          }
      } else {
        __builtin_amdgcn_s_barrier();
        __builtin_amdgcn_sched_barrier(0);
      }
      bf16x8 av[2][2];
#pragma unroll
      for (int mm = 0; mm < 2; ++mm)
#pragma unroll
        for (int kk = 0; kk < 2; ++kk) {
          unsigned off = (unsigned)(wm * 128 + p * 32 + mm * 16 + lrow) * 128u +
                         ((unsigned)((kk * 4 + lk) ^ (lrow & 7)) << 4);
          av[mm][kk] = *(const bf16x8*)(bufc + A_OFF + off);
        }
      __builtin_amdgcn_sched_barrier(0);
      __builtin_amdgcn_s_setprio(1);
#pragma unroll
      for (int mm = 0; mm < 2; ++mm)
#pragma unroll
        for (int n = 0; n < NF; ++n)
#pragma unroll
          for (int kk = 0; kk < 2; ++kk) {
            acc[0][2 * p + mm][n] = __builtin_amdgcn_mfma_f32_16x16x32_bf16(
                av[mm][kk], bv[0][n][kk], acc[0][2 * p + mm][n], 0, 0, 0);
            if (NOPS == 2)
              acc[1][2 * p + mm][n] = __builtin_amdgcn_mfma_f32_16x16x32_bf16(
                  av[mm][kk], bv[1][n][kk], acc[1][2 * p + mm][n], 0, 0, 0);
          }
      __builtin_amdgcn_s_setprio(0);
      __builtin_amdgcn_sched_barrier(0);
    }
    __builtin_amdgcn_s_barrier();  // end of K-tile: all reads of bufc done
    c ^= 1;
  }

  // ---------------- epilogue ----------------
  if (EPI == 0) {
    unsigned short* H = (unsigned short*)OutV;
#pragma unroll
    for (int n = 0; n < NF; ++n) {
      int col = bn * BN + wn * (BN / 4) + n * 16 + lrow;
      float bg = bias1 ? bias1[(size_t)z * N + col] : 0.f;
      float bu = bias2 ? bias2[(size_t)z * N + col] : 0.f;
#pragma unroll
      for (int mq = 0; mq < 8; ++mq) {
#pragma unroll
        for (int j = 0; j < 4; ++j) {
          float g = acc[0][mq][n][j] + bg;
          float u = (NOPS == 2 ? acc[1][mq][n][j] : 0.f) + bu;
          float h = g / (1.f + __expf(-g)) * u;
          int row = row0 + wm * 128 + mq * 16 + lk * 4 + j;
          H[(size_t)z * Mz * N + (size_t)row * N + col] = f2bf(h);
        }
      }
    }
  } else {
    float* Out = (float*)OutV;
#pragma unroll
    for (int n = 0; n < NF; ++n) {
      int col = bn * BN + wn * (BN / 4) + n * 16 + lrow;
      float bb = bias1 ? bias1[(size_t)z * N + col] : 0.f;
#pragma unroll
      for (int mq = 0; mq < 8; ++mq) {
#pragma unroll
        for (int j = 0; j < 4; ++j) {
          int rl = wm * 128 + mq * 16 + lk * 4 + j;
          float v = acc[0][mq][n][j] + bb;
          if (EPI == 2) {
            atomicAdd(Out + (size_t)sIds[rl] * Dn + col, sSc[rl] * v);
          } else {
            Out[(size_t)(row0 + rl) * Dn + col] = v;
          }
        }
      }
    }
  }
}

extern "C" void kernel_launch(void* const* d_in, const int* in_sizes, int n_in,
                              void* d_out, int out_size, void* d_ws, size_t ws_size,
                              hipStream_t stream) {
  const float* x      = (const float*)d_in[0];
  const float* gate_w = (const float*)d_in[1];
  const float* up_w   = (const float*)d_in[2];
  const float* up_b   = (const float*)d_in[3];
  const float* gw     = (const float*)d_in[4];
  const float* gb     = (const float*)d_in[5];
  const float* down_w = (const float*)d_in[6];
  const float* down_b = (const float*)d_in[7];
  const float* shg    = (const float*)d_in[8];
  const float* shu    = (const float*)d_in[9];
  const float* shd    = (const float*)d_in[10];
  float* out = (float*)d_out;

  const size_t H_BYTES  = (size_t)En * CAPn * Fn * 2;   // 134 MiB
  const size_t XB_BYTES = (size_t)Tn * Dn * 2;          // 16 MiB
  const size_t WE_BYTES = (size_t)En * Fn * Dn * 2;     // 128 MiB each
  const size_t SH_BYTES = (size_t)SHn * Dn * 2;         // 4 MiB each
  const size_t SC_BYTES = (size_t)En * Tn * 4;
  const size_t ID_BYTES = (size_t)En * CAPn * 4;
  const size_t need = H_BYTES + XB_BYTES + 3 * WE_BYTES + 3 * SH_BYTES +
                      SC_BYTES + 2 * ID_BYTES;
  if (ws_size < need) return;

  char* p = (char*)d_ws;
  unsigned short* H    = (unsigned short*)p; p += H_BYTES;
  unsigned short* xb   = (unsigned short*)p; p += XB_BYTES;
  unsigned short* upb  = (unsigned short*)p; p += WE_BYTES;
  unsigned short* gwb  = (unsigned short*)p; p += WE_BYTES;
  unsigned short* dwb  = (unsigned short*)p; p += WE_BYTES;
  unsigned short* shgb = (unsigned short*)p; p += SH_BYTES;
  unsigned short* shub = (unsigned short*)p; p += SH_BYTES;
  unsigned short* shdb = (unsigned short*)p; p += SH_BYTES;
  float* scores = (float*)p; p += SC_BYTES;
  int* ids      = (int*)p;  p += ID_BYTES;
  float* osc    = (float*)p;

  kcvt<<<2048, 256, 0, stream>>>(x, xb, Tn * Dn / 8);
  kscores<<<Tn, 256, 0, stream>>>(x, gate_w, scores);
  kselect<<<En, 256, 0, stream>>>(scores, ids, osc);
  kcvt<<<2048, 256, 0, stream>>>(up_w, upb, En * Fn * Dn / 8);
  kcvt<<<2048, 256, 0, stream>>>(gw, gwb, En * Fn * Dn / 8);
  kcvt<<<2048, 256, 0, stream>>>(down_w, dwb, En * Dn * Fn / 8);
  kcvt<<<256, 256, 0, stream>>>(shg, shgb, SHn * Dn / 8);
  kcvt<<<256, 256, 0, stream>>>(shu, shub, SHn * Dn / 8);
  kcvt<<<256, 256, 0, stream>>>(shd, shdb, Dn * SHn / 8);

  // shared GLU: M=Tn, N=SHn, K=Dn -> H[Tn][SHn]
  kgemm8<128, 2, false, 0><<<(Tn / 256) * (SHn / 128), 512, 0, stream>>>(
      xb, nullptr, shgb, shub, nullptr, nullptr, nullptr, H,
      SHn, Tn, Dn, Tn / 256, SHn / 128);
  // shared down: M=Tn, N=Dn, K=SHn -> out (dense store, covers all of d_out)
  kgemm8<256, 1, false, 1><<<(Tn / 256) * (Dn / 256), 512, 0, stream>>>(
      H, nullptr, shdb, nullptr, nullptr, nullptr, nullptr, out,
      Dn, Tn, SHn, Tn / 256, Dn / 256);
  // expert GLU: M=CAP (gathered), N=Fn, K=Dn, z=E -> H[E][CAP][Fn]
  kgemm8<128, 2, true, 0><<<(CAPn / 256) * (Fn / 128) * En, 512, 0, stream>>>(
      xb, ids, gwb, upb, gb, up_b, nullptr, H,
      Fn, CAPn, Dn, CAPn / 256, Fn / 128);
  // expert down: M=CAP, N=Dn, K=Fn, z=E -> scatter-add into out
  kgemm8<256, 1, false, 2><<<(CAPn / 256) * (Dn / 256) * En, 512, 0, stream>>>(
      H, ids, dwb, nullptr, down_b, nullptr, osc, out,
      Dn, CAPn, Fn, CAPn / 256, Dn / 256);
}

// Round 4
// 994.215 us; speedup vs baseline: 1.0803x; 1.0803x over previous
//
#include <hip/hip_runtime.h>
#include <hip/hip_bf16.h>

#define Tn 8192
#define Dn 1024
#define Fn 4096
#define SHn 2048
#define En 16
#define CAPn 1024

typedef __bf16 bf16_t;
typedef bf16_t bf16x8 __attribute__((ext_vector_type(8)));
typedef float f32x4 __attribute__((ext_vector_type(4)));

__device__ __forceinline__ unsigned short f2bf(float f) {
  unsigned int u = __builtin_bit_cast(unsigned int, f);
  u += 0x7FFFu + ((u >> 16) & 1u);
  return (unsigned short)(u >> 16);
}
__device__ __forceinline__ unsigned int pack2(float a, float b) {
  return (unsigned int)f2bf(a) | ((unsigned int)f2bf(b) << 16);
}

__device__ __forceinline__ void gload16(const void* g, void* l) {
  __builtin_amdgcn_global_load_lds(
      (const __attribute__((address_space(1))) unsigned int*)g,
      (__attribute__((address_space(3))) unsigned int*)l, 16, 0, 0);
}

// ---------------- fp32 -> bf16 convert ----------------
__global__ __launch_bounds__(256) void kcvt(const float* __restrict__ s,
                                            unsigned short* __restrict__ d, int n8) {
  int i = blockIdx.x * 256 + threadIdx.x;
  int stride = gridDim.x * 256;
  const float4* sv = (const float4*)s;
  for (; i < n8; i += stride) {
    float4 a = sv[2 * i], b = sv[2 * i + 1];
    uint4 u = { pack2(a.x, a.y), pack2(a.z, a.w), pack2(b.x, b.y), pack2(b.z, b.w) };
    ((uint4*)d)[i] = u;
  }
}

// ---------------- gate scores: sigmoid(x @ gate_w^T), stored [E][T] ----------------
__global__ __launch_bounds__(256) void kscores(const float* __restrict__ x,
                                               const float* __restrict__ gw,
                                               float* __restrict__ sc) {
  __shared__ float sx[Dn];
  int tid = threadIdx.x, tok = blockIdx.x;
  ((float4*)sx)[tid] = ((const float4*)(x + (size_t)tok * Dn))[tid];
  __syncthreads();
  int e = tid >> 4, kl = tid & 15;
  const float4* w = (const float4*)(gw + e * Dn);
  const float4* xv = (const float4*)sx;
  float acc = 0.f;
#pragma unroll
  for (int j = 0; j < 16; ++j) {
    float4 a = w[kl + 16 * j], b = xv[kl + 16 * j];
    acc += a.x * b.x + a.y * b.y + a.z * b.z + a.w * b.w;
  }
#pragma unroll
  for (int off = 8; off; off >>= 1) acc += __shfl_xor(acc, off, 64);
  if (kl == 0) sc[(size_t)e * Tn + tok] = 1.f / (1.f + expf(-acc));
}

// ---------------- per-expert top-CAP radix select (ties: lowest index) ----------------
__global__ __launch_bounds__(256) void kselect(const float* __restrict__ scores,
                                               int* __restrict__ ids,
                                               float* __restrict__ oscore) {
  __shared__ unsigned int keys[Tn];
  __shared__ unsigned int hist[256];
  __shared__ unsigned int sh_prefix, sh_k, sh_cnt, sh_eq;
  __shared__ int eqlist[1024];
  const int tid = threadIdx.x, e = blockIdx.x;
  const float* row = scores + (size_t)e * Tn;
  for (int i = 0; i < Tn / 256; ++i)
    keys[tid + i * 256] = __float_as_uint(row[tid + i * 256]);
  if (tid == 0) { sh_prefix = 0u; sh_k = CAPn; }
  __syncthreads();
  for (int shift = 24; shift >= 0; shift -= 8) {
    hist[tid] = 0u;
    __syncthreads();
    unsigned int prefix = sh_prefix;
    unsigned int mask = (shift == 24) ? 0u : (0xFFFFFFFFu << (shift + 8));
    for (int i = 0; i < Tn / 256; ++i) {
      unsigned int kk = keys[tid + i * 256];
      if ((kk & mask) == prefix) atomicAdd(&hist[(kk >> shift) & 255], 1u);
    }
    __syncthreads();
    if (tid == 0) {
      unsigned int k = sh_k, c = 0; int b;
      for (b = 255; b >= 0; --b) { c += hist[b]; if (c >= k) break; }
      sh_k = k - (c - hist[b]);
      sh_prefix = prefix | ((unsigned int)b << shift);
    }
    __syncthreads();
  }
  const unsigned int thr = sh_prefix;
  if (tid == 0) { sh_cnt = 0u; sh_eq = 0u; }
  __syncthreads();
  const int base = e * CAPn;
  for (int i = 0; i < Tn / 256; ++i) {
    int t = tid + i * 256;
    unsigned int kk = keys[t];
    if (kk > thr) {
      unsigned int p = atomicAdd(&sh_cnt, 1u);
      ids[base + p] = t;
      oscore[base + p] = __uint_as_float(kk);
    } else if (kk == thr) {
      unsigned int p = atomicAdd(&sh_eq, 1u);
      if (p < 1024u) eqlist[p] = t;
    }
  }
  __syncthreads();
  if (tid == 0) {
    int need = CAPn - (int)sh_cnt;
    int m = (int)sh_eq; if (m > 1024) m = 1024;
    for (int j = 0; j < need; ++j) {
      int best = 1 << 30, bi = 0;
      for (int i2 = 0; i2 < m; ++i2)
        if (eqlist[i2] < best) { best = eqlist[i2]; bi = i2; }
      eqlist[bi] = 1 << 30;
      ids[base + (int)sh_cnt + j] = best;
      oscore[base + (int)sh_cnt + j] = __uint_as_float(thr);
    }
  }
}

// =====================================================================
// Double-buffered counted-vmcnt GEMM, 512 threads, 8 waves, BM=256, BK=64.
// All 8 next-tile global_load_lds issued at tile top; single vmcnt(8) wait
// (never drains to 0 mid-loop); 2 barriers per K-tile. bm-fastest block
// order + XCD chunk swizzle keeps weight-slab sharers on one XCD.
// GLU: BN=128, two B operands. Down: BN=256, one B.
// EPI: 0 = GLU -> H bf16; 1 = dense fp32 store; 2 = scatter atomicAdd*score
// =====================================================================
template <int BN, int NOPS, bool GATHER, int EPI>
__global__ __launch_bounds__(512, 2) void kgemm8(
    const unsigned short* __restrict__ Ab, const int* __restrict__ idsg,
    const unsigned short* __restrict__ B1b, const unsigned short* __restrict__ B2b,
    const float* __restrict__ bias1, const float* __restrict__ bias2,
    const float* __restrict__ scg, void* __restrict__ OutV,
    int N, int Mz, int K, int MBc, int NBc) {
  constexpr int BM = 256;
  constexpr int NF = (BN / 4) / 16;          // per-wave n fragments
  constexpr int BRPW = BN / 8;               // B rows staged per wave
  constexpr int BISS = BRPW / 8;             // B stage issues per wave (2 or 4)
  constexpr unsigned A_OFF = 0;
  constexpr unsigned B1_OFF = 32768;
  constexpr unsigned B2_OFF = 32768u + (unsigned)BN * 128u;

  __shared__ alignas(16) unsigned char lds[2][65536];
  __shared__ int sIds[BM];
  __shared__ float sSc[BM];

  const int tid = threadIdx.x;
  const int lane = tid & 63, w = tid >> 6;
  const int wm = w >> 2, wn = w & 3;
  const int lrow = lane & 15, lk = lane >> 4;
  const int lr = lane >> 3, lc = lane & 7;
  const int srcb = ((lc ^ lr) << 4);

  const int nwg = gridDim.x;
  const int cpx = nwg >> 3;
  const int bid = blockIdx.x;
  const int swz = (bid & 7) * cpx + (bid >> 3);
  const int bm = swz % MBc;                      // bm fastest: slab sharers adjacent
  const int bn = (swz / MBc) % NBc;
  const int z  = swz / (NBc * MBc);
  const int row0 = bm * BM;

  if (tid < BM) {
    if (GATHER || EPI == 2) {
      sIds[tid] = idsg[z * CAPn + row0 + tid];
      if (EPI == 2) sSc[tid] = scg[z * CAPn + row0 + tid];
    }
  }
  __syncthreads();

  const size_t ks = (size_t)K * 2;  // row stride in bytes
  const unsigned char* Az = (const unsigned char*)Ab + (EPI == 2 ? (size_t)z * Mz * ks : 0);
  const unsigned char* B1z = (const unsigned char*)B1b + (size_t)z * N * ks;
  const unsigned char* B2z = (NOPS == 2) ? (const unsigned char*)B2b + (size_t)z * N * ks : nullptr;

  const unsigned char* aS[4];
#pragma unroll
  for (int i = 0; i < 4; ++i) {
    int rr = w * 32 + 8 * i + lr;
    size_t arow = GATHER ? (size_t)sIds[rr] : (size_t)(row0 + rr);
    aS[i] = Az + arow * ks + srcb;
  }
  const unsigned char* b1S[BISS];
  const unsigned char* b2S[BISS];
#pragma unroll
  for (int i = 0; i < BISS; ++i) {
    int rr = bn * BN + w * BRPW + 8 * i + lr;
    b1S[i] = B1z + (size_t)rr * ks + srcb;
    if (NOPS == 2) b2S[i] = B2z + (size_t)rr * ks + srcb;
  }

  auto STG = [&](int idx, unsigned char* buf, int kb) {
    if (idx < 4) {
      gload16(aS[idx] + kb, buf + A_OFF + (unsigned)(w * 32 + 8 * idx) * 128u);
    } else if (NOPS == 2) {
      if (idx < 6)
        gload16(b1S[idx - 4] + kb, buf + B1_OFF + (unsigned)(w * BRPW + 8 * (idx - 4)) * 128u);
      else
        gload16(b2S[idx - 6] + kb, buf + B2_OFF + (unsigned)(w * BRPW + 8 * (idx - 6)) * 128u);
    } else {
      gload16(b1S[idx - 4] + kb, buf + B1_OFF + (unsigned)(w * BRPW + 8 * (idx - 4)) * 128u);
    }
  };

  f32x4 acc[NOPS][8][NF];
#pragma unroll
  for (int o = 0; o < NOPS; ++o)
#pragma unroll
    for (int m = 0; m < 8; ++m)
#pragma unroll
      for (int n = 0; n < NF; ++n) acc[o][m][n] = {0.f, 0.f, 0.f, 0.f};

  // prologue: stage tile 0 into lds[0]
#pragma unroll
  for (int i = 0; i < 8; ++i) STG(i, lds[0], 0);

  const int NT = K >> 6;
  int c = 0;
  for (int t = 0; t < NT; ++t) {
    unsigned char* bufc = lds[c];
    unsigned char* bufn = lds[c ^ 1];
    if (t + 1 < NT) {
      const int kb = (t + 1) * 128;
#pragma unroll
      for (int i = 0; i < 8; ++i) STG(i, bufn, kb);
      asm volatile("s_waitcnt vmcnt(8)" ::: "memory");   // tile-t loads done; next-tile stays in flight
    } else {
      asm volatile("s_waitcnt vmcnt(0)" ::: "memory");
    }
    __builtin_amdgcn_s_barrier();
    __builtin_amdgcn_sched_barrier(0);

    bf16x8 bv[NOPS][NF][2];
#pragma unroll
    for (int n = 0; n < NF; ++n)
#pragma unroll
      for (int kk = 0; kk < 2; ++kk) {
        unsigned off = (unsigned)(wn * (BN / 4) + n * 16 + lrow) * 128u +
                       ((unsigned)((kk * 4 + lk) ^ (lrow & 7)) << 4);
        bv[0][n][kk] = *(const bf16x8*)(bufc + B1_OFF + off);
        if (NOPS == 2) bv[1][n][kk] = *(const bf16x8*)(bufc + B2_OFF + off);
      }
#pragma unroll
    for (int p = 0; p < 4; ++p) {
      bf16x8 av[2][2];
#pragma unroll
      for (int mm = 0; mm < 2; ++mm)
#pragma unroll
        for (int kk = 0; kk < 2; ++kk) {
          unsigned off = (unsigned)(wm * 128 + p * 32 + mm * 16 + lrow) * 128u +
                         ((unsigned)((kk * 4 + lk) ^ (lrow & 7)) << 4);
          av[mm][kk] = *(const bf16x8*)(bufc + A_OFF + off);
        }
      __builtin_amdgcn_s_setprio(1);
#pragma unroll
      for (int mm = 0; mm < 2; ++mm)
#pragma unroll
        for (int n = 0; n < NF; ++n)
#pragma unroll
          for (int kk = 0; kk < 2; ++kk) {
            acc[0][2 * p + mm][n] = __builtin_amdgcn_mfma_f32_16x16x32_bf16(
                av[mm][kk], bv[0][n][kk], acc[0][2 * p + mm][n], 0, 0, 0);
            if (NOPS == 2)
              acc[1][2 * p + mm][n] = __builtin_amdgcn_mfma_f32_16x16x32_bf16(
                  av[mm][kk], bv[1][n][kk], acc[1][2 * p + mm][n], 0, 0, 0);
          }
      __builtin_amdgcn_s_setprio(0);
    }
    __builtin_amdgcn_sched_barrier(0);
    __builtin_amdgcn_s_barrier();  // all reads of bufc done before next tile overwrites it
    c ^= 1;
  }

  // ---------------- epilogue ----------------
  if (EPI == 0) {
    unsigned short* H = (unsigned short*)OutV;
#pragma unroll
    for (int n = 0; n < NF; ++n) {
      int col = bn * BN + wn * (BN / 4) + n * 16 + lrow;
      float bg = bias1 ? bias1[(size_t)z * N + col] : 0.f;
      float bu = bias2 ? bias2[(size_t)z * N + col] : 0.f;
#pragma unroll
      for (int mq = 0; mq < 8; ++mq) {
#pragma unroll
        for (int j = 0; j < 4; ++j) {
          float g = acc[0][mq][n][j] + bg;
          float u = (NOPS == 2 ? acc[1][mq][n][j] : 0.f) + bu;
          float h = g / (1.f + __expf(-g)) * u;
          int row = row0 + wm * 128 + mq * 16 + lk * 4 + j;
          H[(size_t)z * Mz * N + (size_t)row * N + col] = f2bf(h);
        }
      }
    }
  } else {
    float* Out = (float*)OutV;
#pragma unroll
    for (int n = 0; n < NF; ++n) {
      int col = bn * BN + wn * (BN / 4) + n * 16 + lrow;
      float bb = bias1 ? bias1[(size_t)z * N + col] : 0.f;
#pragma unroll
      for (int mq = 0; mq < 8; ++mq) {
#pragma unroll
        for (int j = 0; j < 4; ++j) {
          int rl = wm * 128 + mq * 16 + lk * 4 + j;
          float v = acc[0][mq][n][j] + bb;
          if (EPI == 2) {
            atomicAdd(Out + (size_t)sIds[rl] * Dn + col, sSc[rl] * v);
          } else {
            Out[(size_t)(row0 + rl) * Dn + col] = v;
          }
        }
      }
    }
  }
}

extern "C" void kernel_launch(void* const* d_in, const int* in_sizes, int n_in,
                              void* d_out, int out_size, void* d_ws, size_t ws_size,
                              hipStream_t stream) {
  const float* x      = (const float*)d_in[0];
  const float* gate_w = (const float*)d_in[1];
  const float* up_w   = (const float*)d_in[2];
  const float* up_b   = (const float*)d_in[3];
  const float* gw     = (const float*)d_in[4];
  const float* gb     = (const float*)d_in[5];
  const float* down_w = (const float*)d_in[6];
  const float* down_b = (const float*)d_in[7];
  const float* shg    = (const float*)d_in[8];
  const float* shu    = (const float*)d_in[9];
  const float* shd    = (const float*)d_in[10];
  float* out = (float*)d_out;

  const size_t H_BYTES  = (size_t)En * CAPn * Fn * 2;   // 134 MiB
  const size_t XB_BYTES = (size_t)Tn * Dn * 2;          // 16 MiB
  const size_t WE_BYTES = (size_t)En * Fn * Dn * 2;     // 128 MiB each
  const size_t SH_BYTES = (size_t)SHn * Dn * 2;         // 4 MiB each
  const size_t SC_BYTES = (size_t)En * Tn * 4;
  const size_t ID_BYTES = (size_t)En * CAPn * 4;
  const size_t need = H_BYTES + XB_BYTES + 3 * WE_BYTES + 3 * SH_BYTES +
                      SC_BYTES + 2 * ID_BYTES;
  if (ws_size < need) return;

  char* p = (char*)d_ws;
  unsigned short* H    = (unsigned short*)p; p += H_BYTES;
  unsigned short* xb   = (unsigned short*)p; p += XB_BYTES;
  unsigned short* upb  = (unsigned short*)p; p += WE_BYTES;
  unsigned short* gwb  = (unsigned short*)p; p += WE_BYTES;
  unsigned short* dwb  = (unsigned short*)p; p += WE_BYTES;
  unsigned short* shgb = (unsigned short*)p; p += SH_BYTES;
  unsigned short* shub = (unsigned short*)p; p += SH_BYTES;
  unsigned short* shdb = (unsigned short*)p; p += SH_BYTES;
  float* scores = (float*)p; p += SC_BYTES;
  int* ids      = (int*)p;  p += ID_BYTES;
  float* osc    = (float*)p;

  kcvt<<<2048, 256, 0, stream>>>(x, xb, Tn * Dn / 8);
  kscores<<<Tn, 256, 0, stream>>>(x, gate_w, scores);
  kselect<<<En, 256, 0, stream>>>(scores, ids, osc);
  kcvt<<<2048, 256, 0, stream>>>(up_w, upb, En * Fn * Dn / 8);
  kcvt<<<2048, 256, 0, stream>>>(gw, gwb, En * Fn * Dn / 8);
  kcvt<<<2048, 256, 0, stream>>>(down_w, dwb, En * Dn * Fn / 8);
  kcvt<<<256, 256, 0, stream>>>(shg, shgb, SHn * Dn / 8);
  kcvt<<<256, 256, 0, stream>>>(shu, shub, SHn * Dn / 8);
  kcvt<<<256, 256, 0, stream>>>(shd, shdb, Dn * SHn / 8);

  // shared GLU: M=Tn, N=SHn, K=Dn -> H[Tn][SHn]
  kgemm8<128, 2, false, 0><<<(Tn / 256) * (SHn / 128), 512, 0, stream>>>(
      xb, nullptr, shgb, shub, nullptr, nullptr, nullptr, H,
      SHn, Tn, Dn, Tn / 256, SHn / 128);
  // shared down: M=Tn, N=Dn, K=SHn -> out (dense store, covers all of d_out)
  kgemm8<256, 1, false, 1><<<(Tn / 256) * (Dn / 256), 512, 0, stream>>>(
      H, nullptr, shdb, nullptr, nullptr, nullptr, nullptr, out,
      Dn, Tn, SHn, Tn / 256, Dn / 256);
  // expert GLU: M=CAP (gathered), N=Fn, K=Dn, z=E -> H[E][CAP][Fn]
  kgemm8<128, 2, true, 0><<<(CAPn / 256) * (Fn / 128) * En, 512, 0, stream>>>(
      xb, ids, gwb, upb, gb, up_b, nullptr, H,
      Fn, CAPn, Dn, CAPn / 256, Fn / 128);
  // expert down: M=CAP, N=Dn, K=Fn, z=E -> scatter-add into out
  kgemm8<256, 1, false, 2><<<(CAPn / 256) * (Dn / 256) * En, 512, 0, stream>>>(
      H, ids, dwb, nullptr, down_b, nullptr, osc, out,
      Dn, CAPn, Fn, CAPn / 256, Dn / 256);
}